// Round 2
// baseline (3152.490 us; speedup 1.0000x reference)
//
#include <hip/hip_runtime.h>

#define BB 4
#define NT 256
#define NZ 384
#define NX 384
#define NREC 128
#define NZX (NZ*NX)        // 147456
#define BNZX (BB*NZX)      // 589824
#define DT 0.001f
#define INV_DH2 0.01f      // 1/(10*10)

#define TILE 48            // interior tile
#define HALO 8             // = K
#define KSTEP 8            // time steps per grid sync
#define REG 64             // TILE + 2*HALO, LDS region edge
#define NTB 8              // tiles per axis = 384/48
#define NBLK (NTB*NTB*BB)  // 256 blocks
#define NOUT (NT/KSTEP)    // 32 outer iterations

// Zero global ping-pong buffers, precompute c2dt2 = (vp*DT)^2, zero barrier.
__global__ void wave_init(const float* __restrict__ vp, float* __restrict__ ws) {
    int idx = blockIdx.x * blockDim.x + threadIdx.x;
    if (idx < BNZX) {
        ws[idx] = 0.0f;                  // A0
        ws[BNZX + idx] = 0.0f;           // A1
        ws[2*BNZX + idx] = 0.0f;         // B0
        ws[3*BNZX + idx] = 0.0f;         // B1
    }
    if (idx < NZX) { float v = vp[idx] * DT; ws[4*BNZX + idx] = v * v; }
    if (idx == 0) ((unsigned*)(ws + 4*BNZX + NZX))[0] = 0u;
}

__device__ inline void grid_sync(unsigned* cnt, unsigned gen) {
    __syncthreads();
    if (threadIdx.x == 0) {
        __threadfence();                               // release prior writes
        atomicAdd(cnt, 1u);                            // device-scope by default
        unsigned target = gen * (unsigned)NBLK;
        while (__hip_atomic_load(cnt, __ATOMIC_ACQUIRE,
                                 __HIP_MEMORY_SCOPE_AGENT) < target) {
            __builtin_amdgcn_s_sleep(1);
        }
    }
    __syncthreads();
    __threadfence();                                   // acquire for all threads
}

__global__ __launch_bounds__(256, 2)
void wave_tiled(float* __restrict__ ws, const float* __restrict__ x,
                const int* __restrict__ src_y, const int* __restrict__ src_x,
                const int* __restrict__ rec_y, const int* __restrict__ rec_x,
                float* __restrict__ y) {
    __shared__ float bufA[REG*REG];
    __shared__ float bufB[REG*REG];
    __shared__ float lc2[REG*REG];
    __shared__ int   recIdx[NREC];
    __shared__ int   recCnt;

    float* A0 = ws;              float* A1 = ws + BNZX;
    float* B0 = ws + 2*BNZX;     float* B1 = ws + 3*BNZX;
    const float* c2g = ws + 4*BNZX;
    unsigned* cnt = (unsigned*)(ws + 4*BNZX + NZX);

    const int tid = threadIdx.x;
    const int blk = blockIdx.x;
    const int b  = blk >> 6;
    const int tz = (blk >> 3) & 7;
    const int tx = blk & 7;
    const int oz = tz * TILE - HALO;
    const int ox = tx * TILE - HALO;
    const int sy = src_y[b], sx = src_x[b];
    const float* xb = x + b * NT;

    if (tid == 0) recCnt = 0;
    __syncthreads();
    for (int r = tid; r < NREC; r += 256) {
        if (rec_y[r] / TILE == tz && rec_x[r] / TILE == tx) {
            int p = atomicAdd(&recCnt, 1);
            recIdx[p] = r;
        }
    }
    // c2 tile (constant over time) -> LDS once
    for (int k = tid; k < REG*REG; k += 256) {
        int i = k >> 6, j = k & 63;
        int gz = oz + i, gx = ox + j;
        bool in = (gz >= 0 && gz < NZ && gx >= 0 && gx < NX);
        lc2[k] = in ? c2g[gz * NX + gx] : 0.0f;
    }

    float* P0 = A0; float* P1 = A1;    // read pair
    float* Q0 = B0; float* Q1 = B1;    // write pair
    float* cur = bufA; float* prv = bufB;

    for (int o = 0; o < NOUT; ++o) {
        // stage 64x64 region of both time levels into LDS
        for (int k = tid; k < REG*REG; k += 256) {
            int i = k >> 6, j = k & 63;
            int gz = oz + i, gx = ox + j;
            bool in = (gz >= 0 && gz < NZ && gx >= 0 && gx < NX);
            size_t g = (size_t)b * NZX + gz * NX + gx;
            cur[k] = in ? P0[g] : 0.0f;
            prv[k] = in ? P1[g] : 0.0f;
        }
        __syncthreads();

        for (int s = 1; s <= KSTEP; ++s) {
            const int t = (o << 3) + s - 1;
            const int lo = s, rows = REG - 2 * s;
            const int ty = tid >> 2;           // 0..63 -> row
            const int jb = (tid & 3) << 4;     // 16-col strip
            if (ty < rows) {
                const int i = lo + ty;
                const int gz = oz + i;
                if (gz >= 0 && gz < NZ) {
                    const bool zin = (gz > 0 && gz < NZ - 1);
                    #pragma unroll
                    for (int jj = 0; jj < 16; ++jj) {
                        const int j = jb + jj;
                        const int gx = ox + j;
                        if (gx < 0 || gx >= NX) continue;
                        const int k = (i << 6) + j;
                        const float c = cur[k];
                        float lap = 0.0f;
                        if (zin && gx > 0 && gx < NX - 1)
                            lap = (cur[k - 64] + cur[k + 64] +
                                   cur[k - 1]  + cur[k + 1] - 4.0f * c) * INV_DH2;
                        float hn = 2.0f * c - prv[k] + lc2[k] * lap;
                        if (gz == sy && gx == sx) hn += xb[t];
                        prv[k] = hn;
                    }
                }
            }
            __syncthreads();
            { float* tmp = cur; cur = prv; prv = tmp; }
            // gather receivers owned by this tile (interior => valid every step)
            for (int g = tid; g < recCnt; g += 256) {
                int r = recIdx[g];
                y[(size_t)t * (BB * NREC) + b * NREC + r] =
                    cur[(rec_y[r] - oz) * REG + (rec_x[r] - ox)];
            }
        }

        // write back interior (both time levels) to the write pair
        for (int k = tid; k < TILE*TILE; k += 256) {
            int i = k / TILE + HALO, j = k % TILE + HALO;
            size_t g = (size_t)b * NZX + (size_t)(oz + i) * NX + (ox + j);
            Q0[g] = cur[(i << 6) + j];
            Q1[g] = prv[(i << 6) + j];
        }
        grid_sync(cnt, (unsigned)(o + 1));
        { float* t0 = P0; P0 = Q0; Q0 = t0; }
        { float* t1 = P1; P1 = Q1; Q1 = t1; }
    }
}

extern "C" void kernel_launch(void* const* d_in, const int* in_sizes, int n_in,
                              void* d_out, int out_size, void* d_ws, size_t ws_size,
                              hipStream_t stream) {
    const float* x     = (const float*)d_in[0];
    const float* vp    = (const float*)d_in[1];
    const int*   src_y = (const int*)d_in[2];
    const int*   src_x = (const int*)d_in[3];
    const int*   rec_y = (const int*)d_in[4];
    const int*   rec_x = (const int*)d_in[5];
    float* y  = (float*)d_out;
    float* ws = (float*)d_ws;   // 4*BNZX state + NZX c2 + 1 barrier word (~10 MB)

    wave_init<<<(BNZX + 255) / 256, 256, 0, stream>>>(vp, ws);
    wave_tiled<<<NBLK, 256, 0, stream>>>(ws, x, src_y, src_x, rec_y, rec_x, y);
}

// Round 3
// 2132.163 us; speedup vs baseline: 1.4785x; 1.4785x over previous
//
#include <hip/hip_runtime.h>

#define BB 4
#define NT 256
#define NZ 384
#define NX 384
#define NREC 128
#define NZX (NZ*NX)        // 147456
#define BNZX (BB*NZX)      // 589824
#define DT 0.001f
#define INV_DH2 0.01f      // 1/(10*10)

#define TILE 48            // interior tile edge
#define HALO 8             // halo width = KSTEP
#define KSTEP 8            // time steps per grid sync
#define REG 64             // TILE + 2*HALO
#define NTB 8              // 384/48
#define NBLK (NTB*NTB*BB)  // 256 blocks == 256 CUs -> co-resident
#define NOUT (NT/KSTEP)    // 32 outer iterations / grid barriers

// d_ws is poisoned 0xAA every call: only the barrier counter must be zeroed
// (all global frame cells are written before they are read).
__global__ void wave_init(unsigned* cnt) {
    if (blockIdx.x == 0 && threadIdx.x == 0) *cnt = 0u;
}

__device__ inline void grid_sync(unsigned* cnt, unsigned gen) {
    __syncthreads();
    if (threadIdx.x == 0) {
        __threadfence();                       // release (flushes for cross-XCD)
        atomicAdd(cnt, 1u);                    // device-scope
        unsigned target = gen * (unsigned)NBLK;
        while (__hip_atomic_load(cnt, __ATOMIC_ACQUIRE,
                                 __HIP_MEMORY_SCOPE_AGENT) < target)
            __builtin_amdgcn_s_sleep(1);
    }
    __syncthreads();
    __threadfence();                           // acquire
}

// lane = column (stride-1 LDS: conflict-free). Each thread owns 16 rows x 1 col.
// prv + c2dt2 levels in registers; cur level double-buffered in LDS.
__global__ __launch_bounds__(256)
void wave_tiled(float* __restrict__ ws, const float* __restrict__ vp,
                const float* __restrict__ x,
                const int* __restrict__ src_y, const int* __restrict__ src_x,
                const int* __restrict__ rec_y, const int* __restrict__ rec_x,
                float* __restrict__ y) {
    __shared__ float bufA[REG*REG];
    __shared__ float bufB[REG*REG];
    __shared__ int recLoc[NREC];   // (ly<<6)|lx
    __shared__ int recOut[NREC];   // b*NREC + r
    __shared__ int recCnt;

    unsigned* cnt = (unsigned*)(ws + 4*BNZX);

    const int tid = threadIdx.x;
    const int col = tid & 63;
    const int r0  = (tid >> 6) << 4;           // 0,16,32,48
    const int blk = blockIdx.x;
    const int b  = blk >> 6;
    const int tz = (blk >> 3) & 7;
    const int tx = blk & 7;
    const int oz = tz*TILE - HALO, ox = tx*TILE - HALO;
    const int sy = src_y[b], sx = src_x[b];
    const float* xb = x + b*NT;
    const int gx = ox + col;
    const bool gxIn  = (gx >= 0 && gx < NX);
    const bool gxInt = (gx > 0  && gx < NX-1);

    if (tid == 0) recCnt = 0;
    __syncthreads();
    for (int r = tid; r < NREC; r += 256) {
        int ry = rec_y[r], rx = rec_x[r];
        if (ry/TILE == tz && rx/TILE == tx) {
            int p = atomicAdd(&recCnt, 1);
            recLoc[p] = ((ry - oz) << 6) | (rx - ox);
            recOut[p] = b*NREC + r;
        }
    }

    float prv[16], c2r[16];
    #pragma unroll
    for (int m = 0; m < 16; ++m) {
        const int i = r0 + m, gz = oz + i;
        prv[m] = 0.f;
        bufA[(i<<6)+col] = 0.f;
        bufB[(i<<6)+col] = 0.f;
        const bool in = gxIn && gz >= 0 && gz < NZ;
        const float v = in ? vp[gz*NX + gx] * DT : 0.f;
        c2r[m] = v*v;
    }
    __syncthreads();

    for (int o = 0; o < NOUT; ++o) {
        #pragma unroll 1
        for (int s = 1; s <= KSTEP; ++s) {
            const int t = o*KSTEP + s - 1;
            const float xv = xb[t];
            const float* rb = (s & 1) ? bufA : bufB;
            float*       wb = (s & 1) ? bufB : bufA;
            const int lo = s, hi = 63 - s;
            const bool colAct = (col >= lo && col <= hi) && gxIn;

            float up = rb[(max(r0-1,0)<<6) + col];
            float ce = rb[(r0<<6) + col];
            #pragma unroll
            for (int m = 0; m < 16; ++m) {
                const int i = r0 + m;
                const float dn = rb[(min(i+1,63)<<6) + col];
                const int gz = oz + i;
                if (colAct && i >= lo && i <= hi && gz >= 0 && gz < NZ) {
                    float lap = 0.f;
                    if (gxInt && gz > 0 && gz < NZ-1) {
                        const float lf = rb[(i<<6) + col - 1];
                        const float rt = rb[(i<<6) + col + 1];
                        lap = (up + dn + lf + rt - 4.f*ce) * INV_DH2;
                    }
                    float hn = 2.f*ce - prv[m] + c2r[m]*lap;
                    if (gz == sy && gx == sx) hn += xv;
                    prv[m] = ce;
                    wb[(i<<6)+col] = hn;
                }
                up = ce; ce = dn;
            }
            __syncthreads();
            // receivers live in tile interiors => valid every step
            for (int g2 = tid; g2 < recCnt; g2 += 256)
                y[(size_t)t*(BB*NREC) + recOut[g2]] = wb[recLoc[g2]];
        }

        // --- halo exchange: write own interior 8-frame (cur in bufA, prv in regs)
        float* Gc = ws + (size_t)(o & 1)*2*BNZX;   // ping-pong frame buffers
        float* Gp = Gc + BNZX;
        {
            const bool colF = (col >= HALO && col < REG-HALO);
            const bool colM = (col >= 2*HALO && col < REG-2*HALO);
            if (colF) {
                #pragma unroll
                for (int m = 0; m < 16; ++m) {
                    const int i = r0 + m;
                    const bool rowF = (i >= HALO && i < REG-HALO);
                    const bool rowM = (i >= 2*HALO && i < REG-2*HALO);
                    if (rowF && !(colM && rowM)) {
                        const size_t g = (size_t)b*NZX + (size_t)(oz+i)*NX + gx;
                        Gc[g] = bufA[(i<<6)+col];
                        Gp[g] = prv[m];
                    }
                }
            }
        }
        grid_sync(cnt, (unsigned)(o+1));
        // --- read 8-wide halo ring (neighbors' frames) into bufA / prv regs
        {
            const bool colH = (col < HALO || col >= REG-HALO);
            #pragma unroll
            for (int m = 0; m < 16; ++m) {
                const int i = r0 + m;
                if (colH || i < HALO || i >= REG-HALO) {
                    const int gz = oz + i;
                    if (gxIn && gz >= 0 && gz < NZ) {
                        const size_t g = (size_t)b*NZX + (size_t)gz*NX + gx;
                        bufA[(i<<6)+col] = Gc[g];
                        prv[m] = Gp[g];
                    }
                    // out-of-domain stays 0 (never read)
                }
            }
        }
        __syncthreads();
    }
}

extern "C" void kernel_launch(void* const* d_in, const int* in_sizes, int n_in,
                              void* d_out, int out_size, void* d_ws, size_t ws_size,
                              hipStream_t stream) {
    const float* x     = (const float*)d_in[0];
    const float* vp    = (const float*)d_in[1];
    const int*   src_y = (const int*)d_in[2];
    const int*   src_x = (const int*)d_in[3];
    const int*   rec_y = (const int*)d_in[4];
    const int*   rec_x = (const int*)d_in[5];
    float* y  = (float*)d_out;
    float* ws = (float*)d_ws;   // 4*BNZX frame floats + barrier counter (~9.4 MB)

    wave_init<<<1, 64, 0, stream>>>((unsigned*)(ws + 4*BNZX));
    wave_tiled<<<NBLK, 256, 0, stream>>>(ws, vp, x, src_y, src_x, rec_y, rec_x, y);
}

// Round 4
// 707.993 us; speedup vs baseline: 4.4527x; 3.0116x over previous
//
#include <hip/hip_runtime.h>

#define BB 4
#define NT 256
#define NZ 384
#define NX 384
#define NREC 128
#define NZX (NZ*NX)        // 147456
#define BNZX (BB*NZX)      // 589824
#define DT 0.001f
#define INV_DH2 0.01f      // 1/(10*10)

#define TILE 48            // interior tile edge
#define HALO 8             // halo width = KSTEP
#define KSTEP 8            // time steps per grid sync
#define REG 64             // TILE + 2*HALO
#define NTB 8              // 384/48
#define NBLK (NTB*NTB*BB)  // 256 blocks == 256 CUs -> co-resident
#define NOUT (NT/KSTEP)    // 32 outer iterations / grid barriers
#define NTHR 512           // 8 waves/block, 8 rows per thread

__global__ void wave_init(unsigned* cnt) {
    if (blockIdx.x == 0 && threadIdx.x == 0) *cnt = 0u;
}

// No threadfence: halo data moves via agent-scope atomics (coherent at LLC),
// so no L2 writeback/invalidate is needed. __syncthreads drains each wave's
// outstanding stores (vmcnt) before the arrival atomic.
__device__ inline void grid_sync(unsigned* cnt, unsigned gen) {
    __syncthreads();
    if (threadIdx.x == 0) {
        __hip_atomic_fetch_add(cnt, 1u, __ATOMIC_RELAXED, __HIP_MEMORY_SCOPE_AGENT);
        const unsigned target = gen * (unsigned)NBLK;
        while (__hip_atomic_load(cnt, __ATOMIC_RELAXED,
                                 __HIP_MEMORY_SCOPE_AGENT) < target)
            __builtin_amdgcn_s_sleep(2);
    }
    __syncthreads();
}

// lane = column (stride-1 LDS, conflict-free). Thread owns 8 rows x 1 col.
// prv + c2dt2 in registers; cur level double-buffered in LDS.
__global__ __launch_bounds__(NTHR)
void wave_tiled(float* __restrict__ ws, const float* __restrict__ vp,
                const float* __restrict__ x,
                const int* __restrict__ src_y, const int* __restrict__ src_x,
                const int* __restrict__ rec_y, const int* __restrict__ rec_x,
                float* __restrict__ y) {
    __shared__ float bufA[REG*REG];
    __shared__ float bufB[REG*REG];
    __shared__ int recLoc[NREC];
    __shared__ int recOut[NREC];
    __shared__ int recCnt;

    unsigned* cnt = (unsigned*)(ws + 4*BNZX);

    const int tid = threadIdx.x;
    const int col = tid & 63;
    const int r0  = (tid >> 6) << 3;           // 0,8,...,56
    const int blk = blockIdx.x;
    const int b  = blk >> 6;
    const int tz = (blk >> 3) & 7;
    const int tx = blk & 7;
    const int oz = tz*TILE - HALO, ox = tx*TILE - HALO;
    const int sy = src_y[b], sx = src_x[b];
    const float* xb = x + b*NT;
    const int gx = ox + col;
    const bool gxIn  = (gx >= 0 && gx < NX);
    const bool gxInt = (gx > 0  && gx < NX-1);

    if (tid == 0) recCnt = 0;
    __syncthreads();
    for (int r = tid; r < NREC; r += NTHR) {
        int ry = rec_y[r], rx = rec_x[r];
        if (ry/TILE == tz && rx/TILE == tx) {
            int p = atomicAdd(&recCnt, 1);
            recLoc[p] = ((ry - oz) << 6) | (rx - ox);
            recOut[p] = b*NREC + r;
        }
    }

    float prv[8], c2r[8];
    #pragma unroll
    for (int m = 0; m < 8; ++m) {
        const int i = r0 + m, gz = oz + i;
        prv[m] = 0.f;
        bufA[(i<<6)+col] = 0.f;
        bufB[(i<<6)+col] = 0.f;
        const bool in = gxIn && gz >= 0 && gz < NZ;
        const float v = in ? vp[gz*NX + gx] * DT : 0.f;
        c2r[m] = v*v;
    }
    __syncthreads();

    for (int o = 0; o < NOUT; ++o) {
        #pragma unroll 1
        for (int s = 1; s <= KSTEP; ++s) {
            const int t = o*KSTEP + s - 1;
            const float xv = xb[t];
            const float* rb = (s & 1) ? bufA : bufB;
            float*       wb = (s & 1) ? bufB : bufA;
            const int lo = s, hi = 63 - s;
            const bool colAct = (col >= lo && col <= hi) && gxIn;

            float up = rb[(max(r0-1,0)<<6) + col];
            float ce = rb[(r0<<6) + col];
            #pragma unroll
            for (int m = 0; m < 8; ++m) {
                const int i = r0 + m;
                const float dn = rb[(min(i+1,63)<<6) + col];
                const int gz = oz + i;
                if (colAct && i >= lo && i <= hi && gz >= 0 && gz < NZ) {
                    float lap = 0.f;
                    if (gxInt && gz > 0 && gz < NZ-1) {
                        const float lf = rb[(i<<6) + col - 1];
                        const float rt = rb[(i<<6) + col + 1];
                        lap = (up + dn + lf + rt - 4.f*ce) * INV_DH2;
                    }
                    float hn = 2.f*ce - prv[m] + c2r[m]*lap;
                    if (gz == sy && gx == sx) hn += xv;
                    prv[m] = ce;
                    wb[(i<<6)+col] = hn;
                }
                up = ce; ce = dn;
            }
            __syncthreads();
            for (int g2 = tid; g2 < recCnt; g2 += NTHR)
                y[(size_t)t*(BB*NREC) + recOut[g2]] = wb[recLoc[g2]];
        }

        // --- halo exchange: write own interior 8-frame via agent-scope stores
        float* Gc = ws + (size_t)(o & 1)*2*BNZX;   // ping-pong frame buffers
        float* Gp = Gc + BNZX;
        {
            const bool colF = (col >= HALO && col < REG-HALO);
            const bool colM = (col >= 2*HALO && col < REG-2*HALO);
            if (colF) {
                #pragma unroll
                for (int m = 0; m < 8; ++m) {
                    const int i = r0 + m;
                    const bool rowF = (i >= HALO && i < REG-HALO);
                    const bool rowM = (i >= 2*HALO && i < REG-2*HALO);
                    if (rowF && !(colM && rowM)) {
                        const size_t g = (size_t)b*NZX + (size_t)(oz+i)*NX + gx;
                        __hip_atomic_store(&Gc[g], bufA[(i<<6)+col],
                                           __ATOMIC_RELAXED, __HIP_MEMORY_SCOPE_AGENT);
                        __hip_atomic_store(&Gp[g], prv[m],
                                           __ATOMIC_RELAXED, __HIP_MEMORY_SCOPE_AGENT);
                    }
                }
            }
        }
        grid_sync(cnt, (unsigned)(o+1));
        // --- read 8-wide halo ring (neighbors' frames) via agent-scope loads
        {
            const bool colH = (col < HALO || col >= REG-HALO);
            #pragma unroll
            for (int m = 0; m < 8; ++m) {
                const int i = r0 + m;
                if (colH || i < HALO || i >= REG-HALO) {
                    const int gz = oz + i;
                    if (gxIn && gz >= 0 && gz < NZ) {
                        const size_t g = (size_t)b*NZX + (size_t)gz*NX + gx;
                        bufA[(i<<6)+col] = __hip_atomic_load(&Gc[g],
                            __ATOMIC_RELAXED, __HIP_MEMORY_SCOPE_AGENT);
                        prv[m] = __hip_atomic_load(&Gp[g],
                            __ATOMIC_RELAXED, __HIP_MEMORY_SCOPE_AGENT);
                    }
                }
            }
        }
        __syncthreads();
    }
}

extern "C" void kernel_launch(void* const* d_in, const int* in_sizes, int n_in,
                              void* d_out, int out_size, void* d_ws, size_t ws_size,
                              hipStream_t stream) {
    const float* x     = (const float*)d_in[0];
    const float* vp    = (const float*)d_in[1];
    const int*   src_y = (const int*)d_in[2];
    const int*   src_x = (const int*)d_in[3];
    const int*   rec_y = (const int*)d_in[4];
    const int*   rec_x = (const int*)d_in[5];
    float* y  = (float*)d_out;
    float* ws = (float*)d_ws;   // 4*BNZX frame floats + barrier counter (~9.4 MB)

    wave_init<<<1, 64, 0, stream>>>((unsigned*)(ws + 4*BNZX));
    wave_tiled<<<NBLK, NTHR, 0, stream>>>(ws, vp, x, src_y, src_x, rec_y, rec_x, y);
}

// Round 5
// 583.621 us; speedup vs baseline: 5.4016x; 1.2131x over previous
//
#include <hip/hip_runtime.h>

#define BB 4
#define NT 256
#define NZ 384
#define NX 384
#define NREC 128
#define NZX (NZ*NX)        // 147456
#define BNZX (BB*NZX)      // 589824
#define DT 0.001f
#define INV_DH2 0.01f      // 1/(10*10)

#define TILE 48            // interior tile edge
#define HALO 8             // halo width = KSTEP
#define KSTEP 8            // time steps per grid sync
#define REG 64             // TILE + 2*HALO
#define NTB 8              // 384/48
#define NBLK (NTB*NTB*BB)  // 256 blocks == 256 CUs -> co-resident
#define NOUT (NT/KSTEP)    // 32 outer iterations / grid barriers
#define NTHR 512           // 8 waves/block, 8 rows per thread
#define FSTRIDE 16         // flag spread: 64 B apart -> no line sharing

__global__ void wave_init(unsigned* flags) {
    int i = blockIdx.x * blockDim.x + threadIdx.x;
    if (i < NBLK * FSTRIDE) flags[i] = 0u;
}

// All-to-all flag barrier: zero atomics-RMW, no hot line.
// Arrival = one plain agent-scope store to this block's own 64B-spread slot
// (256 in parallel). Wait = wave 0 polls all 256 flags (64 lanes x 4 loads,
// min-reduce). Halo-store visibility: __syncthreads drains vmcnt(0), so the
// agent-scope halo stores are complete at LLC before the flag store issues
// (same ordering the round-4 kernel relied on).
__device__ inline void grid_sync(unsigned* flags, unsigned gen) {
    __syncthreads();
    if (threadIdx.x < 64) {
        if (threadIdx.x == 0)
            __hip_atomic_store(&flags[blockIdx.x * FSTRIDE], gen,
                               __ATOMIC_RELAXED, __HIP_MEMORY_SCOPE_AGENT);
        const int l = threadIdx.x;
        for (;;) {
            unsigned m0 = __hip_atomic_load(&flags[(l      ) * FSTRIDE],
                              __ATOMIC_RELAXED, __HIP_MEMORY_SCOPE_AGENT);
            unsigned m1 = __hip_atomic_load(&flags[(l +  64) * FSTRIDE],
                              __ATOMIC_RELAXED, __HIP_MEMORY_SCOPE_AGENT);
            unsigned m2 = __hip_atomic_load(&flags[(l + 128) * FSTRIDE],
                              __ATOMIC_RELAXED, __HIP_MEMORY_SCOPE_AGENT);
            unsigned m3 = __hip_atomic_load(&flags[(l + 192) * FSTRIDE],
                              __ATOMIC_RELAXED, __HIP_MEMORY_SCOPE_AGENT);
            unsigned mn = min(min(m0, m1), min(m2, m3));
            if (__all(mn >= gen)) break;
            __builtin_amdgcn_s_sleep(1);
        }
    }
    __syncthreads();
}

// lane = column (stride-1 LDS, conflict-free). Thread owns 8 rows x 1 col.
// prv + c2dt2 in registers; cur level double-buffered in LDS.
__global__ __launch_bounds__(NTHR)
void wave_tiled(float* __restrict__ ws, const float* __restrict__ vp,
                const float* __restrict__ x,
                const int* __restrict__ src_y, const int* __restrict__ src_x,
                const int* __restrict__ rec_y, const int* __restrict__ rec_x,
                float* __restrict__ y) {
    __shared__ float bufA[REG*REG];
    __shared__ float bufB[REG*REG];
    __shared__ int recLoc[NREC];
    __shared__ int recOut[NREC];
    __shared__ int recCnt;

    unsigned* flags = (unsigned*)(ws + 4*BNZX);

    const int tid = threadIdx.x;
    const int col = tid & 63;
    const int r0  = (tid >> 6) << 3;           // 0,8,...,56
    const int blk = blockIdx.x;
    const int b  = blk >> 6;
    const int tz = (blk >> 3) & 7;
    const int tx = blk & 7;
    const int oz = tz*TILE - HALO, ox = tx*TILE - HALO;
    const int sy = src_y[b], sx = src_x[b];
    const float* xb = x + b*NT;
    const int gx = ox + col;
    const bool gxIn  = (gx >= 0 && gx < NX);
    const bool gxInt = (gx > 0  && gx < NX-1);

    if (tid == 0) recCnt = 0;
    __syncthreads();
    for (int r = tid; r < NREC; r += NTHR) {
        int ry = rec_y[r], rx = rec_x[r];
        if (ry/TILE == tz && rx/TILE == tx) {
            int p = atomicAdd(&recCnt, 1);
            recLoc[p] = ((ry - oz) << 6) | (rx - ox);
            recOut[p] = b*NREC + r;
        }
    }

    float prv[8], c2r[8];
    #pragma unroll
    for (int m = 0; m < 8; ++m) {
        const int i = r0 + m, gz = oz + i;
        prv[m] = 0.f;
        bufA[(i<<6)+col] = 0.f;
        bufB[(i<<6)+col] = 0.f;
        const bool in = gxIn && gz >= 0 && gz < NZ;
        const float v = in ? vp[gz*NX + gx] * DT : 0.f;
        c2r[m] = v*v;
    }
    __syncthreads();

    for (int o = 0; o < NOUT; ++o) {
        #pragma unroll 1
        for (int s = 1; s <= KSTEP; ++s) {
            const int t = o*KSTEP + s - 1;
            const float xv = xb[t];
            const float* rb = (s & 1) ? bufA : bufB;
            float*       wb = (s & 1) ? bufB : bufA;
            const int lo = s, hi = 63 - s;
            const bool colAct = (col >= lo && col <= hi) && gxIn;

            float up = rb[(max(r0-1,0)<<6) + col];
            float ce = rb[(r0<<6) + col];
            #pragma unroll
            for (int m = 0; m < 8; ++m) {
                const int i = r0 + m;
                const float dn = rb[(min(i+1,63)<<6) + col];
                const int gz = oz + i;
                if (colAct && i >= lo && i <= hi && gz >= 0 && gz < NZ) {
                    float lap = 0.f;
                    if (gxInt && gz > 0 && gz < NZ-1) {
                        const float lf = rb[(i<<6) + col - 1];
                        const float rt = rb[(i<<6) + col + 1];
                        lap = (up + dn + lf + rt - 4.f*ce) * INV_DH2;
                    }
                    float hn = 2.f*ce - prv[m] + c2r[m]*lap;
                    if (gz == sy && gx == sx) hn += xv;
                    prv[m] = ce;
                    wb[(i<<6)+col] = hn;
                }
                up = ce; ce = dn;
            }
            __syncthreads();
            for (int g2 = tid; g2 < recCnt; g2 += NTHR)
                y[(size_t)t*(BB*NREC) + recOut[g2]] = wb[recLoc[g2]];
        }

        // --- halo exchange: write own interior 8-frame via agent-scope stores
        float* Gc = ws + (size_t)(o & 1)*2*BNZX;   // ping-pong frame buffers
        float* Gp = Gc + BNZX;
        {
            const bool colF = (col >= HALO && col < REG-HALO);
            const bool colM = (col >= 2*HALO && col < REG-2*HALO);
            if (colF) {
                #pragma unroll
                for (int m = 0; m < 8; ++m) {
                    const int i = r0 + m;
                    const bool rowF = (i >= HALO && i < REG-HALO);
                    const bool rowM = (i >= 2*HALO && i < REG-2*HALO);
                    if (rowF && !(colM && rowM)) {
                        const size_t g = (size_t)b*NZX + (size_t)(oz+i)*NX + gx;
                        __hip_atomic_store(&Gc[g], bufA[(i<<6)+col],
                                           __ATOMIC_RELAXED, __HIP_MEMORY_SCOPE_AGENT);
                        __hip_atomic_store(&Gp[g], prv[m],
                                           __ATOMIC_RELAXED, __HIP_MEMORY_SCOPE_AGENT);
                    }
                }
            }
        }
        grid_sync(flags, (unsigned)(o+1));
        // --- read 8-wide halo ring (neighbors' frames) via agent-scope loads
        {
            const bool colH = (col < HALO || col >= REG-HALO);
            #pragma unroll
            for (int m = 0; m < 8; ++m) {
                const int i = r0 + m;
                if (colH || i < HALO || i >= REG-HALO) {
                    const int gz = oz + i;
                    if (gxIn && gz >= 0 && gz < NZ) {
                        const size_t g = (size_t)b*NZX + (size_t)gz*NX + gx;
                        bufA[(i<<6)+col] = __hip_atomic_load(&Gc[g],
                            __ATOMIC_RELAXED, __HIP_MEMORY_SCOPE_AGENT);
                        prv[m] = __hip_atomic_load(&Gp[g],
                            __ATOMIC_RELAXED, __HIP_MEMORY_SCOPE_AGENT);
                    }
                }
            }
        }
        __syncthreads();
    }
}

extern "C" void kernel_launch(void* const* d_in, const int* in_sizes, int n_in,
                              void* d_out, int out_size, void* d_ws, size_t ws_size,
                              hipStream_t stream) {
    const float* x     = (const float*)d_in[0];
    const float* vp    = (const float*)d_in[1];
    const int*   src_y = (const int*)d_in[2];
    const int*   src_x = (const int*)d_in[3];
    const int*   rec_y = (const int*)d_in[4];
    const int*   rec_x = (const int*)d_in[5];
    float* y  = (float*)d_out;
    float* ws = (float*)d_ws;   // 4*BNZX frame floats + 256*16 flag words (~9.5 MB)

    wave_init<<<(NBLK*FSTRIDE + 255)/256, 256, 0, stream>>>((unsigned*)(ws + 4*BNZX));
    wave_tiled<<<NBLK, NTHR, 0, stream>>>(ws, vp, x, src_y, src_x, rec_y, rec_x, y);
}

// Round 6
// 413.016 us; speedup vs baseline: 7.6329x; 1.4131x over previous
//
#include <hip/hip_runtime.h>

#define BB 4
#define NT 256
#define NZ 384
#define NX 384
#define NREC 128
#define NZX (NZ*NX)        // 147456
#define BNZX (BB*NZX)      // 589824
#define DT 0.001f
#define INV_DH2 0.01f      // 1/(10*10)

#define TILE 48            // interior tile edge
#define HALO 8             // halo width = KSTEP
#define KSTEP 8            // steps per grid sync
#define REGN 64            // TILE + 2*HALO
#define NBLK 256           // 8x8 tiles x 4 batches = 256 blocks (1/CU)
#define NTHR 512           // 8 waves: wave w owns rows 8w..8w+7, lane = col
#define FSTRIDE 16         // flag spread (64 B) -> no cache-line sharing

__global__ void wave_init(unsigned* flags) {
    int i = blockIdx.x * blockDim.x + threadIdx.x;
    if (i < NBLK * FSTRIDE) flags[i] = 0u;
}

// lane±1 neighbor via DPP (VALU pipe, no LDS). Only the SUM lf+rt is used, so
// shl/shr direction mix-up is harmless; bound_ctrl=1 gives 0 at wave edges
// (cols 0/63 are trapezoid margin or domain edge -> masked by c2i anyway).
__device__ inline float dpp_shl1(float v) {
    return __int_as_float(__builtin_amdgcn_update_dpp(
        0, __float_as_int(v), 0x130 /*WAVE_SHL1*/, 0xf, 0xf, true));
}
__device__ inline float dpp_shr1(float v) {
    return __int_as_float(__builtin_amdgcn_update_dpp(
        0, __float_as_int(v), 0x138 /*WAVE_SHR1*/, 0xf, 0xf, true));
}

// All-to-all flag barrier (no RMW, no hot line): arrival = plain agent-scope
// store to own spread slot; wave 0 polls all 256 flags (64 lanes x 4 loads).
// __syncthreads drains vmcnt(0) so halo stores are at LLC before flag store.
__device__ inline void grid_sync(unsigned* flags, unsigned gen) {
    __syncthreads();
    if (threadIdx.x < 64) {
        if (threadIdx.x == 0)
            __hip_atomic_store(&flags[blockIdx.x * FSTRIDE], gen,
                               __ATOMIC_RELAXED, __HIP_MEMORY_SCOPE_AGENT);
        const int l = threadIdx.x;
        for (;;) {
            unsigned m0 = __hip_atomic_load(&flags[(l      ) * FSTRIDE],
                              __ATOMIC_RELAXED, __HIP_MEMORY_SCOPE_AGENT);
            unsigned m1 = __hip_atomic_load(&flags[(l +  64) * FSTRIDE],
                              __ATOMIC_RELAXED, __HIP_MEMORY_SCOPE_AGENT);
            unsigned m2 = __hip_atomic_load(&flags[(l + 128) * FSTRIDE],
                              __ATOMIC_RELAXED, __HIP_MEMORY_SCOPE_AGENT);
            unsigned m3 = __hip_atomic_load(&flags[(l + 192) * FSTRIDE],
                              __ATOMIC_RELAXED, __HIP_MEMORY_SCOPE_AGENT);
            unsigned mn = min(min(m0, m1), min(m2, m3));
            if (__all(mn >= gen)) break;
            __builtin_amdgcn_s_sleep(1);
        }
    }
    __syncthreads();
}

__global__ __launch_bounds__(NTHR)
void wave_tiled(float* __restrict__ ws, const float* __restrict__ vp,
                const float* __restrict__ x,
                const int* __restrict__ src_y, const int* __restrict__ src_x,
                const int* __restrict__ rec_y, const int* __restrict__ rec_x,
                float* __restrict__ y) {
    __shared__ float bnd[2][16][REGN];   // [step parity][2*wave+{top,bot}][col]
    __shared__ int recLoc[NREC], recOut[NREC];
    __shared__ int recCnt;

    unsigned* flags = (unsigned*)(ws + 4*BNZX);

    const int tid = threadIdx.x;
    const int col = tid & 63;
    const int w   = tid >> 6;
    const int r0  = w << 3;
    const int blk = blockIdx.x;
    const int b  = blk >> 6;
    const int tz = (blk >> 3) & 7;
    const int tx = blk & 7;
    const int oz = tz*TILE - HALO, ox = tx*TILE - HALO;
    const int gx = ox + col;
    const int sy = src_y[b], sx = src_x[b];
    const float* xb = x + b*NT;

    if (tid == 0) recCnt = 0;
    for (int k = tid; k < 16*REGN; k += NTHR) ((float*)bnd[0])[k] = 0.f;
    __syncthreads();
    for (int r = tid; r < NREC; r += NTHR) {
        int ry = rec_y[r], rx = rec_x[r];
        if (ry/TILE == tz && rx/TILE == tx) {
            int p = atomicAdd(&recCnt, 1);
            recLoc[p] = ((ry - oz) << 6) | (rx - ox);
            recOut[p] = b*NREC + r;
        }
    }

    // per-thread column state: 8 rows in registers
    float cur[8], prv[8], c2i[8];
    #pragma unroll
    for (int m = 0; m < 8; ++m) {
        cur[m] = 0.f; prv[m] = 0.f;
        const int gz = oz + r0 + m;
        const bool inner = (gz > 0 && gz < NZ-1 && gx > 0 && gx < NX-1);
        const float v = inner ? vp[gz*NX + gx] * DT : 0.f;
        c2i[m] = v * v * INV_DH2;    // 0 at domain edge / out of domain -> lap masked
    }
    const bool srcCol = (gx == sx);
    const int  srcM   = sy - oz - r0;      // source row within my rows if in [0,8)
    const int  iuUp   = (2*w-1 < 0) ? 0 : 2*w-1;     // clamped: garbage-ok margins
    const int  iuDn   = (2*w+2 > 15) ? 15 : 2*w+2;
    __syncthreads();

    #pragma unroll 1
    for (int t = 0; t < NT; ++t) {
        const int pr = t & 1, pw = pr ^ 1;
        // neighbor waves' boundary rows (time t)
        const float upB = bnd[pr][iuUp][col];
        const float dnB = bnd[pr][iuDn][col];

        float hn[8];
        #pragma unroll
        for (int m = 0; m < 8; ++m) {
            const float ce = cur[m];
            const float up = (m == 0) ? upB : cur[m-1];
            const float dn = (m == 7) ? dnB : cur[m+1];
            const float lf = dpp_shl1(ce);
            const float rt = dpp_shr1(ce);
            const float s  = (up + dn) + (lf + rt);
            hn[m] = fmaf(2.f, ce, -prv[m]) + c2i[m] * fmaf(-4.f, ce, s);
        }
        #pragma unroll
        for (int m = 0; m < 8; ++m) { prv[m] = cur[m]; cur[m] = hn[m]; }

        // source injection (single owning thread per tile containing it)
        if (srcCol && (unsigned)srcM < 8u) {
            const float xv = xb[t];
            #pragma unroll
            for (int m = 0; m < 8; ++m) if (m == srcM) cur[m] += xv;
        }
        // receivers (tile-interior cells, valid every step)
        for (int p = 0; p < recCnt; ++p) {
            const int rl = recLoc[p];
            if ((rl & 63) == col) {
                const int rm = (rl >> 6) - r0;
                if ((unsigned)rm < 8u) {
                    float v = 0.f;
                    #pragma unroll
                    for (int m = 0; m < 8; ++m) if (m == rm) v = cur[m];
                    y[(size_t)t * (BB*NREC) + recOut[p]] = v;
                }
            }
        }
        // publish boundary rows for step t+1
        bnd[pw][2*w  ][col] = cur[0];
        bnd[pw][2*w+1][col] = cur[7];

        if ((t & 7) == 7 && t < NT-1) {
            const int o = t >> 3;
            float* Gc = ws + (size_t)(o & 1) * 2*BNZX;   // ping-pong frames
            float* Gp = Gc + BNZX;
            // frame store (8-wide band just inside interior), straight from regs
            const bool colF = (col >= HALO   && col < REGN-HALO);
            const bool colM = (col >= 2*HALO && col < REGN-2*HALO);
            #pragma unroll
            for (int m = 0; m < 8; ++m) {
                const int i = r0 + m;
                const bool rowF = (i >= HALO   && i < REGN-HALO);
                const bool rowM = (i >= 2*HALO && i < REGN-2*HALO);
                if (colF && rowF && !(colM && rowM)) {
                    const size_t g = (size_t)b*NZX + (size_t)(oz+i)*NX + gx;
                    __hip_atomic_store(&Gc[g], cur[m],
                                       __ATOMIC_RELAXED, __HIP_MEMORY_SCOPE_AGENT);
                    __hip_atomic_store(&Gp[g], prv[m],
                                       __ATOMIC_RELAXED, __HIP_MEMORY_SCOPE_AGENT);
                }
            }
            grid_sync(flags, (unsigned)(o + 1));
            // ring read straight into registers (loads batched, no LDS round-trip)
            const bool colH = (col < HALO || col >= REGN-HALO);
            const bool gxIn = (gx >= 0 && gx < NX);
            #pragma unroll
            for (int m = 0; m < 8; ++m) {
                const int i = r0 + m;
                if (colH || i < HALO || i >= REGN-HALO) {
                    const int gz = oz + i;
                    if (gxIn && gz >= 0 && gz < NZ) {
                        const size_t g = (size_t)b*NZX + (size_t)gz*NX + gx;
                        cur[m] = __hip_atomic_load(&Gc[g],
                                     __ATOMIC_RELAXED, __HIP_MEMORY_SCOPE_AGENT);
                        prv[m] = __hip_atomic_load(&Gp[g],
                                     __ATOMIC_RELAXED, __HIP_MEMORY_SCOPE_AGENT);
                    } else { cur[m] = 0.f; prv[m] = 0.f; }
                }
            }
            // refresh boundary rows (ring cells changed)
            bnd[pw][2*w  ][col] = cur[0];
            bnd[pw][2*w+1][col] = cur[7];
        }
        __syncthreads();
    }
}

extern "C" void kernel_launch(void* const* d_in, const int* in_sizes, int n_in,
                              void* d_out, int out_size, void* d_ws, size_t ws_size,
                              hipStream_t stream) {
    const float* x     = (const float*)d_in[0];
    const float* vp    = (const float*)d_in[1];
    const int*   src_y = (const int*)d_in[2];
    const int*   src_x = (const int*)d_in[3];
    const int*   rec_y = (const int*)d_in[4];
    const int*   rec_x = (const int*)d_in[5];
    float* y  = (float*)d_out;
    float* ws = (float*)d_ws;   // 4*BNZX frame floats + 256*16 flag words (~9.5 MB)

    wave_init<<<(NBLK*FSTRIDE + 255)/256, 256, 0, stream>>>((unsigned*)(ws + 4*BNZX));
    wave_tiled<<<NBLK, NTHR, 0, stream>>>(ws, vp, x, src_y, src_x, rec_y, rec_x, y);
}

// Round 7
// 275.356 us; speedup vs baseline: 11.4488x; 1.4999x over previous
//
#include <hip/hip_runtime.h>

#define BB 4
#define NT 256
#define NZ 384
#define NX 384
#define NREC 128
#define NZX (NZ*NX)        // 147456
#define BNZX (BB*NZX)      // 589824
#define DT 0.001f
#define INV_DH2 0.01f      // 1/(10*10)

#define TILE 48            // interior tile edge
#define HALO 8             // halo width = KSTEP
#define REGN 64            // TILE + 2*HALO
#define NBLK 256           // 8x8 tiles x 4 batches (1 block/CU)
#define NTHR 512           // 8 waves: wave w owns rows 8w..8w+7, lane = col
#define FSTRIDE 16         // flag spread (64 B) -> no line sharing

__global__ void wave_init(unsigned* flags) {
    int i = blockIdx.x * blockDim.x + threadIdx.x;
    if (i < NBLK * FSTRIDE) flags[i] = 0u;
}

__device__ inline float dpp_shl1(float v) {
    return __int_as_float(__builtin_amdgcn_update_dpp(
        0, __float_as_int(v), 0x130 /*WAVE_SHL1*/, 0xf, 0xf, true));
}
__device__ inline float dpp_shr1(float v) {
    return __int_as_float(__builtin_amdgcn_update_dpp(
        0, __float_as_int(v), 0x138 /*WAVE_SHR1*/, 0xf, 0xf, true));
}

// Neighbor-only sync: arrival = plain agent-scope store to own spread flag;
// wait = wave 0, lanes 0..7 poll the <=8 neighbor flags (others poll own).
// 2-deep ping-pong frames are safe under neighbor-only sync: B overwrites
// frame k-2 only after observing neighbor flags >= k-1 (exchange k-1), which
// implies neighbors finished reading frame k-2. No global coupling.
__device__ inline void grid_sync(unsigned* flags, unsigned gen, int nbId) {
    __syncthreads();   // drains vmcnt(0): frame stores at LLC before flag store
    if (threadIdx.x < 64) {
        if (threadIdx.x == 0)
            __hip_atomic_store(&flags[blockIdx.x * FSTRIDE], gen,
                               __ATOMIC_RELAXED, __HIP_MEMORY_SCOPE_AGENT);
        for (;;) {
            unsigned f = __hip_atomic_load(&flags[nbId * FSTRIDE],
                             __ATOMIC_RELAXED, __HIP_MEMORY_SCOPE_AGENT);
            if (__all(f >= gen)) break;
            __builtin_amdgcn_s_sleep(1);
        }
    }
    __syncthreads();
}

__global__ __launch_bounds__(NTHR)
void wave_tiled(float* __restrict__ ws, const float* __restrict__ vp,
                const float* __restrict__ x,
                const int* __restrict__ src_y, const int* __restrict__ src_x,
                const int* __restrict__ rec_y, const int* __restrict__ rec_x,
                float* __restrict__ y) {
    __shared__ float bnd[2][16][REGN];   // [parity][2*wave+{top,bot}][col]
    __shared__ float recBuf[NREC][8];    // receiver samples, flushed per window
    __shared__ float xs[NT];             // this batch's source trace
    __shared__ int recLoc[NREC], recOut[NREC];
    __shared__ int recCnt;

    unsigned* flags = (unsigned*)(ws + 4*BNZX);

    const int tid = threadIdx.x;
    const int col = tid & 63;
    const int w   = tid >> 6;
    const int r0  = w << 3;
    const int blk = blockIdx.x;
    const int b  = blk >> 6;
    const int tz = (blk >> 3) & 7;
    const int tx = blk & 7;
    const int oz = tz*TILE - HALO, ox = tx*TILE - HALO;
    const int gx = ox + col;
    const int sy = src_y[b], sx = src_x[b];

    if (tid == 0) recCnt = 0;
    for (int k = tid; k < 16*REGN; k += NTHR) ((float*)bnd[0])[k] = 0.f;
    for (int k = tid; k < NT; k += NTHR) xs[k] = x[b*NT + k];
    __syncthreads();
    for (int r = tid; r < NREC; r += NTHR) {
        int ry = rec_y[r], rx = rec_x[r];
        if (ry/TILE == tz && rx/TILE == tx) {
            int p = atomicAdd(&recCnt, 1);
            recLoc[p] = ((ry - oz) << 6) | (rx - ox);
            recOut[p] = b*NREC + r;
        }
    }
    __syncthreads();

    // per-thread receiver ownership cache (cap 4, LDS-loop fallback)
    int myN = 0, myM[4], myP[4];
    bool ovf = false;
    for (int p = 0; p < recCnt; ++p) {
        int rl = recLoc[p];
        if ((rl & 63) == col) {
            int rm = (rl >> 6) - r0;
            if ((unsigned)rm < 8u) {
                if (myN < 4) { myM[myN] = rm; myP[myN] = p; ++myN; }
                else ovf = true;
            }
        }
    }

    // neighbor ids for the sync (lanes 0..7 of wave 0; others self)
    int nbId = blk;
    if (tid < 8) {
        int d = tid + (tid >= 4);            // 0..8 skipping center 4
        int nz2 = tz + d/3 - 1, nx2 = tx + d%3 - 1;
        if ((unsigned)nz2 < 8u && (unsigned)nx2 < 8u)
            nbId = (b << 6) | (nz2 << 3) | nx2;
    }

    // per-thread column state: 8 rows in registers
    float cur[8], prv[8], c2i[8];
    #pragma unroll
    for (int m = 0; m < 8; ++m) {
        cur[m] = 0.f; prv[m] = 0.f;
        const int gz = oz + r0 + m;
        const bool inner = (gz > 0 && gz < NZ-1 && gx > 0 && gx < NX-1);
        const float v = inner ? vp[gz*NX + gx] * DT : 0.f;
        c2i[m] = v * v * INV_DH2;    // 0 at edges -> lap auto-masked
    }
    const bool srcCol = (gx == sx);
    const int  srcM   = sy - oz - r0;
    const int  iuUp   = (2*w-1 < 0) ? 0 : 2*w-1;
    const int  iuDn   = (2*w+2 > 15) ? 15 : 2*w+2;
    __syncthreads();

    #pragma unroll 1
    for (int t = 0; t < NT; ++t) {
        const int pr = t & 1, pw = pr ^ 1;
        const float upB = bnd[pr][iuUp][col];
        const float dnB = bnd[pr][iuDn][col];

        float hn[8];
        #pragma unroll
        for (int m = 0; m < 8; ++m) {
            const float ce = cur[m];
            const float up = (m == 0) ? upB : cur[m-1];
            const float dn = (m == 7) ? dnB : cur[m+1];
            const float lf = dpp_shl1(ce);
            const float rt = dpp_shr1(ce);
            const float s  = (up + dn) + (lf + rt);
            hn[m] = fmaf(2.f, ce, -prv[m]) + c2i[m] * fmaf(-4.f, ce, s);
        }
        #pragma unroll
        for (int m = 0; m < 8; ++m) { prv[m] = cur[m]; cur[m] = hn[m]; }

        if (srcCol && (unsigned)srcM < 8u) {
            const float xv = xs[t];
            #pragma unroll
            for (int m = 0; m < 8; ++m) if (m == srcM) cur[m] += xv;
        }
        // receiver sampling -> LDS buffer (no global ops in the step loop)
        {
            const int s2 = t & 7;
            if (ovf) {
                for (int p = 0; p < recCnt; ++p) {
                    int rl = recLoc[p];
                    if ((rl & 63) == col) {
                        int rm = (rl >> 6) - r0;
                        if ((unsigned)rm < 8u) {
                            float v = cur[0];
                            #pragma unroll
                            for (int m = 1; m < 8; ++m) if (rm == m) v = cur[m];
                            recBuf[p][s2] = v;
                        }
                    }
                }
            } else {
                #pragma unroll
                for (int k = 0; k < 4; ++k) {
                    if (k < myN) {
                        float v = cur[0];
                        #pragma unroll
                        for (int m = 1; m < 8; ++m) if (myM[k] == m) v = cur[m];
                        recBuf[myP[k]][s2] = v;
                    }
                }
            }
        }
        bnd[pw][2*w  ][col] = cur[0];
        bnd[pw][2*w+1][col] = cur[7];

        if ((t & 7) == 7) {
            const int o = t >> 3;
            __syncthreads();   // recBuf writes of this window visible
            for (int k = tid; k < recCnt*8; k += NTHR) {
                int p = k >> 3, s2 = k & 7;
                y[(size_t)((o<<3)+s2)*(BB*NREC) + recOut[p]] = recBuf[p][s2];
            }
            if (t < NT-1) {
                float* Gc = ws + (size_t)(o & 1) * 2*BNZX;   // ping-pong frames
                float* Gp = Gc + BNZX;
                const bool colF = (col >= HALO   && col < REGN-HALO);
                const bool colM = (col >= 2*HALO && col < REGN-2*HALO);
                #pragma unroll
                for (int m = 0; m < 8; ++m) {
                    const int i = r0 + m;
                    const bool rowF = (i >= HALO   && i < REGN-HALO);
                    const bool rowM = (i >= 2*HALO && i < REGN-2*HALO);
                    if (colF && rowF && !(colM && rowM)) {
                        const size_t g = (size_t)b*NZX + (size_t)(oz+i)*NX + gx;
                        __hip_atomic_store(&Gc[g], cur[m],
                                           __ATOMIC_RELAXED, __HIP_MEMORY_SCOPE_AGENT);
                        __hip_atomic_store(&Gp[g], prv[m],
                                           __ATOMIC_RELAXED, __HIP_MEMORY_SCOPE_AGENT);
                    }
                }
                grid_sync(flags, (unsigned)(o + 1), nbId);
                const bool colH = (col < HALO || col >= REGN-HALO);
                const bool gxIn = (gx >= 0 && gx < NX);
                #pragma unroll
                for (int m = 0; m < 8; ++m) {
                    const int i = r0 + m;
                    if (colH || i < HALO || i >= REGN-HALO) {
                        const int gz = oz + i;
                        if (gxIn && gz >= 0 && gz < NZ) {
                            const size_t g = (size_t)b*NZX + (size_t)gz*NX + gx;
                            cur[m] = __hip_atomic_load(&Gc[g],
                                         __ATOMIC_RELAXED, __HIP_MEMORY_SCOPE_AGENT);
                            prv[m] = __hip_atomic_load(&Gp[g],
                                         __ATOMIC_RELAXED, __HIP_MEMORY_SCOPE_AGENT);
                        } else { cur[m] = 0.f; prv[m] = 0.f; }
                    }
                }
                bnd[pw][2*w  ][col] = cur[0];
                bnd[pw][2*w+1][col] = cur[7];
            }
        }
        __syncthreads();
    }
}

extern "C" void kernel_launch(void* const* d_in, const int* in_sizes, int n_in,
                              void* d_out, int out_size, void* d_ws, size_t ws_size,
                              hipStream_t stream) {
    const float* x     = (const float*)d_in[0];
    const float* vp    = (const float*)d_in[1];
    const int*   src_y = (const int*)d_in[2];
    const int*   src_x = (const int*)d_in[3];
    const int*   rec_y = (const int*)d_in[4];
    const int*   rec_x = (const int*)d_in[5];
    float* y  = (float*)d_out;
    float* ws = (float*)d_ws;   // 4*BNZX frame floats + 256*16 flag words (~9.5 MB)

    wave_init<<<(NBLK*FSTRIDE + 255)/256, 256, 0, stream>>>((unsigned*)(ws + 4*BNZX));
    wave_tiled<<<NBLK, NTHR, 0, stream>>>(ws, vp, x, src_y, src_x, rec_y, rec_x, y);
}